// Round 4
// baseline (213.517 us; speedup 1.0000x reference)
//
#include <hip/hip_runtime.h>
#include <math.h>

#define BB  4
#define SS  1024
#define DD  512
#define HH  8
#define DHD 64
#define PL  2097152      // elements per Q/K/V/Ob plane (also B*S*D)
#define WPL 262144       // elements per W plane

constexpr float LN_EPS = 1e-5f;

using half4 = __attribute__((ext_vector_type(4))) _Float16;
using half8 = __attribute__((ext_vector_type(8))) _Float16;
using f32x4 = __attribute__((ext_vector_type(4))) float;

__device__ __forceinline__ half8 negh(half8 a) {
    union { half8 h; unsigned int u[4]; } t;
    t.h = a;
    #pragma unroll
    for (int i = 0; i < 4; ++i) t.u[i] ^= 0x80008000u;
    return t.h;
}
// 64-wide swizzled rows (XOR (row&7)<<3, 8-half granules): conflict-free b128
__device__ __forceinline__ half8 ldh64(const unsigned short* p, int row, int col) {
    return *(const half8*)(p + row * 64 + (col ^ ((row & 7) << 3)));
}
// packed f32x2 -> f16x2 (RTZ), as raw u32
__device__ __forceinline__ unsigned int cvtpk(float a, float b) {
    union { decltype(__builtin_amdgcn_cvt_pkrtz(0.f, 0.f)) v; unsigned int u; } t;
    t.v = __builtin_amdgcn_cvt_pkrtz(a, b);
    return t.u;
}
#define MFMA16(acc, a, b) acc = __builtin_amdgcn_mfma_f32_16x16x32_f16(a, b, acc, 0, 0, 0)

// ---------------------------------------------------------------------------
// Kernel 0: fp32 complex -> fp16 r/i planes, TILE-BLOCKED layout:
// plane stored as [m/128][d/64][128][64] so proj's K-step strips are 16KB
// contiguous (HBM-stream friendly) instead of 128B-at-1KB-stride.
// ---------------------------------------------------------------------------
__global__ __launch_bounds__(256)
void cvt_kernel(const float2* __restrict__ s0, const float2* __restrict__ s1,
                const float2* __restrict__ s2, unsigned short* __restrict__ dst,
                int planeElems) {
    const int z = blockIdx.y;
    const float2* src = z == 0 ? s0 : (z == 1 ? s1 : s2);
    unsigned short* base = dst + (size_t)z * 2 * planeElems;
    const int idx = (blockIdx.x * 256 + threadIdx.x) * 2;   // complex index (even)
    float4 t = *(const float4*)(src + idx);
    const int m = idx >> 9;          // row
    const int d = idx & 511;         // col (even)
    const int ob = (((m >> 7) << 3) + (d >> 6)) * 8192 + ((m & 127) << 6) + (d & 63);
    union { _Float16 h[2]; unsigned int u; } r, i;
    r.h[0] = (_Float16)t.x; r.h[1] = (_Float16)t.z;
    i.h[0] = (_Float16)t.y; i.h[1] = (_Float16)t.w;
    *(unsigned int*)(base + ob) = r.u;
    *(unsigned int*)(base + planeElems + ob) = i.u;
}

// ---------------------------------------------------------------------------
// Kernel 1: complex projection (unchanged from round 2).
// 128x128 tile, 4 waves 2x2, single-buffered 64KB LDS, 2 blocks/CU,
// global_load_lds staging from the blocked layout with source-side swizzle.
// ---------------------------------------------------------------------------
__global__ __launch_bounds__(256, 2)
void proj_kernel(const unsigned short* __restrict__ XP,
                 const unsigned short* __restrict__ WP,
                 const float2* __restrict__ bq, const float2* __restrict__ bk,
                 const float2* __restrict__ bv,
                 unsigned short* __restrict__ QG, unsigned short* __restrict__ KG,
                 unsigned short* __restrict__ VG) {
    const unsigned short* XR = XP + (size_t)blockIdx.z * 2 * PL;
    const unsigned short* XI = XR + PL;
    const unsigned short* WRp = WP + (size_t)blockIdx.z * 2 * WPL;
    const unsigned short* WIp = WRp + WPL;
    const float2* bias; unsigned short* outP;
    if (blockIdx.z == 0)      { bias = bq; outP = QG; }
    else if (blockIdx.z == 1) { bias = bk; outP = KG; }
    else                      { bias = bv; outP = VG; }
    const bool isV = (blockIdx.z == 2);

    __shared__ __align__(16) unsigned short Xs[2][128 * 64];
    __shared__ __align__(16) unsigned short Ws[2][128 * 64];

    const int tid  = threadIdx.x;
    const int w    = tid >> 6;
    const int lane = tid & 63;
    const int quad = lane >> 4;
    const int l15  = lane & 15;
    const int wm   = w >> 1;                 // m half of the 128x128 tile
    const int we   = w & 1;                  // e half
    const int m0   = blockIdx.x * 128;
    const int e0   = blockIdx.y * 128;

    const int srow = lane >> 3;              // 0..7
    const int sg   = lane & 7;               // granule within row
    const unsigned short* gplane;
    unsigned short* lb;
    int row0;
    if (w == 0)      { gplane = XR;  row0 = m0; lb = &Xs[0][0]; }
    else if (w == 1) { gplane = XI;  row0 = m0; lb = &Xs[1][0]; }
    else if (w == 2) { gplane = WRp; row0 = e0; lb = &Ws[0][0]; }
    else             { gplane = WIp; row0 = e0; lb = &Ws[1][0]; }
    const unsigned short* gs = gplane + (size_t)row0 * DD + srow * 64 + ((sg ^ srow) << 3);

    f32x4 Sr[4][4], Si[4][4];                // [mf][ef]
    #pragma unroll
    for (int a = 0; a < 4; ++a)
        #pragma unroll
        for (int c = 0; c < 4; ++c) { Sr[a][c] = (f32x4)0.f; Si[a][c] = (f32x4)0.f; }

    for (int s = 0; s < 8; ++s) {
        if (s) __syncthreads();              // prev compute done before overwrite
        const unsigned short* _g = gs + (size_t)s * 8192;   // next 16KB block
        #pragma unroll
        for (int j = 0; j < 16; ++j)
            __builtin_amdgcn_global_load_lds(
                (const __attribute__((address_space(1))) void*)(_g + j * 512),
                (__attribute__((address_space(3))) void*)(lb + j * 512),
                16, 0, 0);
        __syncthreads();                     // vmcnt drain -> tile ready

        #pragma unroll
        for (int kc = 0; kc < 2; ++kc) {
            const int dl = kc * 32 + quad * 8;
            half8 xr[4], xi[4];
            #pragma unroll
            for (int mf = 0; mf < 4; ++mf) {
                const int mr = wm * 64 + mf * 16 + l15;
                xr[mf] = ldh64(Xs[0], mr, dl);
                xi[mf] = ldh64(Xs[1], mr, dl);
            }
            #pragma unroll
            for (int ef = 0; ef < 4; ++ef) {
                const int er = we * 64 + ef * 16 + l15;
                half8 wr  = ldh64(Ws[0], er, dl);
                half8 wi  = ldh64(Ws[1], er, dl);
                half8 wmi = negh(wi);
                #pragma unroll
                for (int mf = 0; mf < 4; ++mf) {
                    MFMA16(Sr[mf][ef], xr[mf], wr);    // Xr.Wr
                    MFMA16(Sr[mf][ef], xi[mf], wmi);   // -Xi.Wi
                    MFMA16(Si[mf][ef], xr[mf], wi);    // Xr.Wi
                    MFMA16(Si[mf][ef], xi[mf], wr);    // Xi.Wr
                }
            }
        }
    }

    // ---- epilogue: + bias, fp16, write planes (V transposed) ----
    #pragma unroll
    for (int ef = 0; ef < 4; ++ef) {
        const int eg  = e0 + we * 64 + ef * 16 + l15;   // global out column
        const int hh  = eg >> 6;                         // head
        const int col = eg & 63;
        float2 bb = bias[eg];
        #pragma unroll
        for (int mf = 0; mf < 4; ++mf) {
            #pragma unroll
            for (int reg = 0; reg < 4; ++reg) {
                int m = m0 + wm * 64 + mf * 16 + quad * 4 + reg;
                int bidx = m >> 10;
                int sidx = m & 1023;
                int bh = bidx * HH + hh;
                union { _Float16 h; unsigned short u; } cr, ci;
                cr.h = (_Float16)(Sr[mf][ef][reg] + bb.x);
                ci.h = (_Float16)(Si[mf][ef][reg] + bb.y);
                size_t o = isV ? ((size_t)bh * DHD + col) * SS + sidx
                               : ((size_t)bh * SS + sidx) * DHD + col;
                outP[0 * PL + o] = cr.u;
                outP[1 * PL + o] = ci.u;
            }
        }
    }
}

// ---------------------------------------------------------------------------
// Kernel 2: fp16 MFMA flash attention, S^T formulation.
// Round-4 fix: DMA staging loop is j<8 (64-row/8KB tile = 8 x 1KB DMAs),
// NOT j<16 (that was proj's 128-row tile count; 16 overflowed each plane
// by 8KB into the neighboring LDS arrays -> round-3 corruption).
//  * K/V staging via global_load_lds: pre-swizzled per-lane SOURCE + linear
//    [64][64] LDS + swizzled ldh64 reads.
//  * softmax: exp2f(x*log2e/8), lacc sums unrounded exps, P packed via
//    v_cvt_pkrtz.
//  * s_setprio(1) around both MFMA clusters (T5).
// ---------------------------------------------------------------------------
#define AWID 72
__global__ __launch_bounds__(256, 2)
void attn_kernel(const unsigned short* __restrict__ QG, const unsigned short* __restrict__ KG,
                 const unsigned short* __restrict__ VG,
                 unsigned short* __restrict__ ObR, unsigned short* __restrict__ ObI) {
    __shared__ __align__(16) unsigned short Ks[2][64 * 64];   // [r,i][k][d] swizzled
    __shared__ __align__(16) unsigned short Vt[2][64 * 64];   // [r,i][d][k] swizzled
    __shared__ __align__(16) unsigned short Ps[2][64 * AWID]; // [r,i][q][k]
    __shared__ float lbuf[2][2][64];                          // [plane][k-half][q]

    const int n   = blockIdx.x;
    const int bh  = (n & 7) * 4 + (n >> 7);       // XCD-local bh group
    const int q0  = ((n >> 3) & 15) * 64;
    const int b   = bh >> 3;
    const int h   = bh & 7;

    const int tid  = threadIdx.x;
    const int w    = tid >> 6;
    const int lane = tid & 63;
    const int quad = lane >> 4;
    const int l15  = lane & 15;
    const int sw   = w & 1;        // q-half (both phases)
    const int tw   = w >> 1;       // k-half (scores) / d-half (PV)

    // ---- DMA staging setup: wave w owns tile {Kr,Ki,Vr,Vi}[w] ----
    const int srow = lane >> 3;    // 0..7 (row within 8-row DMA group)
    const int sg   = lane & 7;     // dest granule; source granule = sg^srow
    const unsigned short* bp;      // lane-resolved base at kt=0
    int jstr, ktmul;
    unsigned short* ld;
    if (w < 2) {   // K plane w: rows k (contiguous 128B rows)
        bp = KG + (size_t)w * PL + (size_t)bh * SS * DHD + srow * DHD + ((sg ^ srow) << 3);
        jstr = 8 * DHD; ktmul = DHD; ld = &Ks[w][0];
    } else {       // V^T plane w-2: rows d (stride SS)
        bp = VG + (size_t)(w - 2) * PL + (size_t)bh * DHD * SS + srow * SS + ((sg ^ srow) << 3);
        jstr = 8 * SS; ktmul = 1; ld = &Vt[w - 2][0];
    }

    // Q in B-layout registers: lane = q col, quad*8+j = d within 32-window
    half8 qfr[2][2], qfi[2][2], qfmi[2][2];       // [qt][kc]
    #pragma unroll
    for (int qt = 0; qt < 2; ++qt)
        #pragma unroll
        for (int kc = 0; kc < 2; ++kc) {
            size_t qa = ((size_t)bh * SS + q0 + sw * 32 + qt * 16 + l15) * DHD + kc * 32 + quad * 8;
            qfr[qt][kc]  = *(const half8*)(QG + qa);
            qfi[qt][kc]  = *(const half8*)(QG + PL + qa);
            qfmi[qt][kc] = negh(qfi[qt][kc]);
        }

    f32x4 acc[2][2][4];            // [qt][dt][PrVr,PrVi,PiVr,PiVi]
    #pragma unroll
    for (int qt = 0; qt < 2; ++qt)
        #pragma unroll
        for (int dt = 0; dt < 2; ++dt)
            #pragma unroll
            for (int p = 0; p < 4; ++p) acc[qt][dt][p] = (f32x4)0.f;
    float lacc[2][2] = {{0.f, 0.f}, {0.f, 0.f}};  // [qt][plane]

    constexpr float EC = 0.18033688011112042f;    // log2(e)/8

    for (int kt = 0; kt < SS; kt += 64) {
        __syncthreads();           // prev PV done reading Ks/Vt/Ps
        // ---- stage K and V^T tiles via DMA (8 x 1KB per wave = 8KB tile) ----
        const unsigned short* g = bp + (size_t)kt * ktmul;
        #pragma unroll
        for (int j = 0; j < 8; ++j)
            __builtin_amdgcn_global_load_lds(
                (const __attribute__((address_space(1))) void*)(g + j * jstr),
                (__attribute__((address_space(3))) void*)(ld + j * 512),
                16, 0, 0);
        __syncthreads();           // vmcnt drain -> tiles ready

        // ---- scores: S^T[k32][q32] for this wave's (tw k-half, sw q-half) ----
        f32x4 Sr[2][2], Si[2][2];   // [kt2][qt]
        #pragma unroll
        for (int a = 0; a < 2; ++a)
            #pragma unroll
            for (int c = 0; c < 2; ++c) { Sr[a][c] = (f32x4)0.f; Si[a][c] = (f32x4)0.f; }
        __builtin_amdgcn_s_setprio(1);
        #pragma unroll
        for (int kc = 0; kc < 2; ++kc) {
            const int dl = kc * 32 + quad * 8;
            #pragma unroll
            for (int kt2 = 0; kt2 < 2; ++kt2) {
                const int krow = tw * 32 + kt2 * 16 + l15;
                half8 akr = ldh64(Ks[0], krow, dl);
                half8 aki = ldh64(Ks[1], krow, dl);
                #pragma unroll
                for (int qt = 0; qt < 2; ++qt) {
                    MFMA16(Sr[kt2][qt], akr, qfr[qt][kc]);    // K_r . Q_r
                    MFMA16(Sr[kt2][qt], aki, qfmi[qt][kc]);   // -K_i . Q_i
                    MFMA16(Si[kt2][qt], aki, qfr[qt][kc]);    // K_i . Q_r
                    MFMA16(Si[kt2][qt], akr, qfi[qt][kc]);    // K_r . Q_i
                }
            }
        }
        __builtin_amdgcn_s_setprio(0);

        // ---- exp -> P (packed b64, q-major), l partial per lane ----
        #pragma unroll
        for (int kt2 = 0; kt2 < 2; ++kt2)
            #pragma unroll
            for (int qt = 0; qt < 2; ++qt) {
                float er0 = exp2f(Sr[kt2][qt][0] * EC), er1 = exp2f(Sr[kt2][qt][1] * EC);
                float er2 = exp2f(Sr[kt2][qt][2] * EC), er3 = exp2f(Sr[kt2][qt][3] * EC);
                float ei0 = exp2f(Si[kt2][qt][0] * EC), ei1 = exp2f(Si[kt2][qt][1] * EC);
                float ei2 = exp2f(Si[kt2][qt][2] * EC), ei3 = exp2f(Si[kt2][qt][3] * EC);
                lacc[qt][0] += (er0 + er1) + (er2 + er3);
                lacc[qt][1] += (ei0 + ei1) + (ei2 + ei3);
                const int qrow = sw * 32 + qt * 16 + l15;
                const int kcol = tw * 32 + kt2 * 16 + quad * 4;
                uint2 pr, pi;
                pr.x = cvtpk(er0, er1); pr.y = cvtpk(er2, er3);
                pi.x = cvtpk(ei0, ei1); pi.y = cvtpk(ei2, ei3);
                *(uint2*)&Ps[0][qrow * AWID + kcol] = pr;
                *(uint2*)&Ps[1][qrow * AWID + kcol] = pi;
            }
        __syncthreads();

        // ---- PV: out tile q32 (sw) x d32 (tw), k64 accumulation ----
        #pragma unroll
        for (int kc = 0; kc < 2; ++kc) {
            half8 ap[2][2];   // [qt][plane]
            #pragma unroll
            for (int qt = 0; qt < 2; ++qt) {
                const int qrow = sw * 32 + qt * 16 + l15;
                ap[qt][0] = *(const half8*)&Ps[0][qrow * AWID + kc * 32 + quad * 8];
                ap[qt][1] = *(const half8*)&Ps[1][qrow * AWID + kc * 32 + quad * 8];
            }
            __builtin_amdgcn_s_setprio(1);
            #pragma unroll
            for (int dt = 0; dt < 2; ++dt) {
                const int drow = tw * 32 + dt * 16 + l15;
                half8 bvr = ldh64(Vt[0], drow, kc * 32 + quad * 8);
                half8 bvi = ldh64(Vt[1], drow, kc * 32 + quad * 8);
                #pragma unroll
                for (int qt = 0; qt < 2; ++qt) {
                    MFMA16(acc[qt][dt][0], ap[qt][0], bvr);
                    MFMA16(acc[qt][dt][1], ap[qt][0], bvi);
                    MFMA16(acc[qt][dt][2], ap[qt][1], bvr);
                    MFMA16(acc[qt][dt][3], ap[qt][1], bvi);
                }
            }
            __builtin_amdgcn_s_setprio(0);
        }
    }

    // ---- combine l: quad-reduce (lane's k-subset -> full k-half), store ----
    __syncthreads();
    #pragma unroll
    for (int qt = 0; qt < 2; ++qt)
        #pragma unroll
        for (int p = 0; p < 2; ++p) {
            float v = lacc[qt][p];
            v += __shfl_xor(v, 16);
            v += __shfl_xor(v, 32);
            if (lane < 16) lbuf[p][tw][sw * 32 + qt * 16 + lane] = v;
        }
    __syncthreads();

    // ---- epilogue: normalize, combine complex, store fp16 planes ----
    #pragma unroll
    for (int qt = 0; qt < 2; ++qt)
        #pragma unroll
        for (int reg = 0; reg < 4; ++reg) {
            const int qloc = sw * 32 + qt * 16 + quad * 4 + reg;
            const float ir = 1.f / (lbuf[0][0][qloc] + lbuf[0][1][qloc]);
            const float ii = 1.f / (lbuf[1][0][qloc] + lbuf[1][1][qloc]);
            #pragma unroll
            for (int dt = 0; dt < 2; ++dt) {
                const int d = tw * 32 + dt * 16 + l15;
                union { _Float16 h; unsigned short u; } cr, ci;
                cr.h = (_Float16)(acc[qt][dt][0][reg] * ir - acc[qt][dt][3][reg] * ii);
                ci.h = (_Float16)(acc[qt][dt][1][reg] * ir + acc[qt][dt][2][reg] * ii);
                size_t o = ((size_t)b * SS + q0 + qloc) * DD + h * DHD + d;
                ObR[o] = cr.u;
                ObI[o] = ci.u;
            }
        }
}

// ---------------------------------------------------------------------------
// Kernel 3: residual + dual LayerNorm over D (biased var, eps inside sqrt)
// ---------------------------------------------------------------------------
__global__ __launch_bounds__(256)
void ln_kernel(const unsigned short* __restrict__ OrP, const unsigned short* __restrict__ OiP,
               const float2* __restrict__ Qin,
               const float* __restrict__ gr, const float* __restrict__ br,
               const float* __restrict__ gi, const float* __restrict__ bi,
               float2* __restrict__ out) {
    const int row = blockIdx.x;           // b*S + s
    const int tid = threadIdx.x;
    const size_t base = (size_t)row * DD;
    const int e0 = 2 * tid, e1 = 2 * tid + 1;

    union { unsigned int u; _Float16 h[2]; } tr, ti;
    tr.u = *(const unsigned int*)(OrP + base + e0);
    ti.u = *(const unsigned int*)(OiP + base + e0);
    float2 r0 = Qin[base + e0];
    float2 r1 = Qin[base + e1];
    float xr0 = (float)tr.h[0] + r0.x;
    float xr1 = (float)tr.h[1] + r1.x;
    float xi0 = (float)ti.h[0] + r0.y;
    float xi1 = (float)ti.h[1] + r1.y;

    float sr = xr0 + xr1;
    float si = xi0 + xi1;
    float qr = xr0 * xr0 + xr1 * xr1;
    float qi = xi0 * xi0 + xi1 * xi1;
    #pragma unroll
    for (int off = 32; off > 0; off >>= 1) {
        sr += __shfl_down(sr, off);
        si += __shfl_down(si, off);
        qr += __shfl_down(qr, off);
        qi += __shfl_down(qi, off);
    }
    __shared__ float red[4][4];
    __shared__ float stat[4];
    int lane = tid & 63, wid = tid >> 6;
    if (lane == 0) { red[wid][0] = sr; red[wid][1] = si; red[wid][2] = qr; red[wid][3] = qi; }
    __syncthreads();
    if (tid == 0) {
        sr = red[0][0] + red[1][0] + red[2][0] + red[3][0];
        si = red[0][1] + red[1][1] + red[2][1] + red[3][1];
        qr = red[0][2] + red[1][2] + red[2][2] + red[3][2];
        qi = red[0][3] + red[1][3] + red[2][3] + red[3][3];
        float mur = sr * (1.f / DD), mui = si * (1.f / DD);
        float vr = qr * (1.f / DD) - mur * mur;
        float vi = qi * (1.f / DD) - mui * mui;
        stat[0] = mur; stat[1] = mui;
        stat[2] = rsqrtf(vr + LN_EPS); stat[3] = rsqrtf(vi + LN_EPS);
    }
    __syncthreads();
    float mur = stat[0], mui = stat[1], rsr = stat[2], rsi = stat[3];
    out[base + e0] = make_float2((xr0 - mur) * rsr * gr[e0] + br[e0],
                                 (xi0 - mui) * rsi * gi[e0] + bi[e0]);
    out[base + e1] = make_float2((xr1 - mur) * rsr * gr[e1] + br[e1],
                                 (xi1 - mui) * rsi * gi[e1] + bi[e1]);
}

// ---------------------------------------------------------------------------
extern "C" void kernel_launch(void* const* d_in, const int* in_sizes, int n_in,
                              void* d_out, int out_size, void* d_ws, size_t ws_size,
                              hipStream_t stream) {
    const float2* q  = (const float2*)d_in[0];
    const float2* k  = (const float2*)d_in[1];
    const float2* v  = (const float2*)d_in[2];
    const float2* Wq = (const float2*)d_in[3];
    const float2* bq = (const float2*)d_in[4];
    const float2* Wk = (const float2*)d_in[5];
    const float2* bk = (const float2*)d_in[6];
    const float2* Wv = (const float2*)d_in[7];
    const float2* bv = (const float2*)d_in[8];
    const float*  gr = (const float*)d_in[9];
    const float*  br = (const float*)d_in[10];
    const float*  gi = (const float*)d_in[11];
    const float*  bi = (const float*)d_in[12];

    // workspace (fp16 elements): X planes, W planes, Q/K/V planes, Ob planes
    unsigned short* XP  = (unsigned short*)d_ws;           // 3*2*PL (blocked)
    unsigned short* WP  = XP + (size_t)6 * PL;             // 3*2*WPL (blocked)
    unsigned short* QG  = WP + (size_t)6 * WPL;            // 2*PL  [BH][S][64]
    unsigned short* KG  = QG + (size_t)2 * PL;             // 2*PL  [BH][S][64]
    unsigned short* VG  = KG + (size_t)2 * PL;             // 2*PL  [BH][64][S] (transposed)
    unsigned short* ObR = VG + (size_t)2 * PL;             // PL
    unsigned short* ObI = ObR + (size_t)PL;                // PL

    cvt_kernel<<<dim3(4096, 3), 256, 0, stream>>>(q, k, v, XP, PL);
    cvt_kernel<<<dim3(512, 3), 256, 0, stream>>>(Wq, Wk, Wv, WP, WPL);
    proj_kernel<<<dim3(32, 4, 3), 256, 0, stream>>>(XP, WP, bq, bk, bv, QG, KG, VG);
    attn_kernel<<<dim3(512), 256, 0, stream>>>(QG, KG, VG, ObR, ObI);
    ln_kernel<<<dim3(BB * SS), 256, 0, stream>>>(ObR, ObI, q, gr, br, gi, bi, (float2*)d_out);
}

// Round 5
// 205.164 us; speedup vs baseline: 1.0407x; 1.0407x over previous
//
#include <hip/hip_runtime.h>
#include <math.h>

#define BB  4
#define SS  1024
#define DD  512
#define HH  8
#define DHD 64
#define PL  2097152      // elements per Q/K/V/Ob plane (also B*S*D)
#define WPL 262144       // elements per W plane

constexpr float LN_EPS = 1e-5f;

using half4 = __attribute__((ext_vector_type(4))) _Float16;
using half8 = __attribute__((ext_vector_type(8))) _Float16;
using f32x4 = __attribute__((ext_vector_type(4))) float;

__device__ __forceinline__ half8 negh(half8 a) {
    union { half8 h; unsigned int u[4]; } t;
    t.h = a;
    #pragma unroll
    for (int i = 0; i < 4; ++i) t.u[i] ^= 0x80008000u;
    return t.h;
}
// 64-wide swizzled rows (XOR (row&7)<<3, 8-half granules): conflict-free b128
__device__ __forceinline__ half8 ldh64(const unsigned short* p, int row, int col) {
    return *(const half8*)(p + row * 64 + (col ^ ((row & 7) << 3)));
}
// packed f32x2 -> f16x2 (RTZ), as raw u32
__device__ __forceinline__ unsigned int cvtpk(float a, float b) {
    union { decltype(__builtin_amdgcn_cvt_pkrtz(0.f, 0.f)) v; unsigned int u; } t;
    t.v = __builtin_amdgcn_cvt_pkrtz(a, b);
    return t.u;
}
// native v_exp_f32 (2^x) — NOT the precise OCML exp2f path
__device__ __forceinline__ float ex2(float x) { return __builtin_amdgcn_exp2f(x); }
#define MFMA16(acc, a, b) acc = __builtin_amdgcn_mfma_f32_16x16x32_f16(a, b, acc, 0, 0, 0)

// ---------------------------------------------------------------------------
// Kernel 0: fp32 complex -> fp16 r/i planes, TILE-BLOCKED layout:
// plane stored as [m/128][d/64][128][64] so proj's K-step strips are 16KB
// contiguous (HBM-stream friendly) instead of 128B-at-1KB-stride.
// ---------------------------------------------------------------------------
__global__ __launch_bounds__(256)
void cvt_kernel(const float2* __restrict__ s0, const float2* __restrict__ s1,
                const float2* __restrict__ s2, unsigned short* __restrict__ dst,
                int planeElems) {
    const int z = blockIdx.y;
    const float2* src = z == 0 ? s0 : (z == 1 ? s1 : s2);
    unsigned short* base = dst + (size_t)z * 2 * planeElems;
    const int idx = (blockIdx.x * 256 + threadIdx.x) * 2;   // complex index (even)
    float4 t = *(const float4*)(src + idx);
    const int m = idx >> 9;          // row
    const int d = idx & 511;         // col (even)
    const int ob = (((m >> 7) << 3) + (d >> 6)) * 8192 + ((m & 127) << 6) + (d & 63);
    union { _Float16 h[2]; unsigned int u; } r, i;
    r.h[0] = (_Float16)t.x; r.h[1] = (_Float16)t.z;
    i.h[0] = (_Float16)t.y; i.h[1] = (_Float16)t.w;
    *(unsigned int*)(base + ob) = r.u;
    *(unsigned int*)(base + planeElems + ob) = i.u;
}

// ---------------------------------------------------------------------------
// Kernel 1: complex projection (unchanged from round 2).
// 128x128 tile, 4 waves 2x2, single-buffered 64KB LDS, 2 blocks/CU,
// global_load_lds staging from the blocked layout with source-side swizzle.
// ---------------------------------------------------------------------------
__global__ __launch_bounds__(256, 2)
void proj_kernel(const unsigned short* __restrict__ XP,
                 const unsigned short* __restrict__ WP,
                 const float2* __restrict__ bq, const float2* __restrict__ bk,
                 const float2* __restrict__ bv,
                 unsigned short* __restrict__ QG, unsigned short* __restrict__ KG,
                 unsigned short* __restrict__ VG) {
    const unsigned short* XR = XP + (size_t)blockIdx.z * 2 * PL;
    const unsigned short* XI = XR + PL;
    const unsigned short* WRp = WP + (size_t)blockIdx.z * 2 * WPL;
    const unsigned short* WIp = WRp + WPL;
    const float2* bias; unsigned short* outP;
    if (blockIdx.z == 0)      { bias = bq; outP = QG; }
    else if (blockIdx.z == 1) { bias = bk; outP = KG; }
    else                      { bias = bv; outP = VG; }
    const bool isV = (blockIdx.z == 2);

    __shared__ __align__(16) unsigned short Xs[2][128 * 64];
    __shared__ __align__(16) unsigned short Ws[2][128 * 64];

    const int tid  = threadIdx.x;
    const int w    = tid >> 6;
    const int lane = tid & 63;
    const int quad = lane >> 4;
    const int l15  = lane & 15;
    const int wm   = w >> 1;                 // m half of the 128x128 tile
    const int we   = w & 1;                  // e half
    const int m0   = blockIdx.x * 128;
    const int e0   = blockIdx.y * 128;

    const int srow = lane >> 3;              // 0..7
    const int sg   = lane & 7;               // granule within row
    const unsigned short* gplane;
    unsigned short* lb;
    int row0;
    if (w == 0)      { gplane = XR;  row0 = m0; lb = &Xs[0][0]; }
    else if (w == 1) { gplane = XI;  row0 = m0; lb = &Xs[1][0]; }
    else if (w == 2) { gplane = WRp; row0 = e0; lb = &Ws[0][0]; }
    else             { gplane = WIp; row0 = e0; lb = &Ws[1][0]; }
    const unsigned short* gs = gplane + (size_t)row0 * DD + srow * 64 + ((sg ^ srow) << 3);

    f32x4 Sr[4][4], Si[4][4];                // [mf][ef]
    #pragma unroll
    for (int a = 0; a < 4; ++a)
        #pragma unroll
        for (int c = 0; c < 4; ++c) { Sr[a][c] = (f32x4)0.f; Si[a][c] = (f32x4)0.f; }

    for (int s = 0; s < 8; ++s) {
        if (s) __syncthreads();              // prev compute done before overwrite
        const unsigned short* _g = gs + (size_t)s * 8192;   // next 16KB block
        #pragma unroll
        for (int j = 0; j < 16; ++j)
            __builtin_amdgcn_global_load_lds(
                (const __attribute__((address_space(1))) void*)(_g + j * 512),
                (__attribute__((address_space(3))) void*)(lb + j * 512),
                16, 0, 0);
        __syncthreads();                     // vmcnt drain -> tile ready

        #pragma unroll
        for (int kc = 0; kc < 2; ++kc) {
            const int dl = kc * 32 + quad * 8;
            half8 xr[4], xi[4];
            #pragma unroll
            for (int mf = 0; mf < 4; ++mf) {
                const int mr = wm * 64 + mf * 16 + l15;
                xr[mf] = ldh64(Xs[0], mr, dl);
                xi[mf] = ldh64(Xs[1], mr, dl);
            }
            #pragma unroll
            for (int ef = 0; ef < 4; ++ef) {
                const int er = we * 64 + ef * 16 + l15;
                half8 wr  = ldh64(Ws[0], er, dl);
                half8 wi  = ldh64(Ws[1], er, dl);
                half8 wmi = negh(wi);
                #pragma unroll
                for (int mf = 0; mf < 4; ++mf) {
                    MFMA16(Sr[mf][ef], xr[mf], wr);    // Xr.Wr
                    MFMA16(Sr[mf][ef], xi[mf], wmi);   // -Xi.Wi
                    MFMA16(Si[mf][ef], xr[mf], wi);    // Xr.Wi
                    MFMA16(Si[mf][ef], xi[mf], wr);    // Xi.Wr
                }
            }
        }
    }

    // ---- epilogue: + bias, fp16, write planes (V transposed) ----
    #pragma unroll
    for (int ef = 0; ef < 4; ++ef) {
        const int eg  = e0 + we * 64 + ef * 16 + l15;   // global out column
        const int hh  = eg >> 6;                         // head
        const int col = eg & 63;
        float2 bb = bias[eg];
        #pragma unroll
        for (int mf = 0; mf < 4; ++mf) {
            #pragma unroll
            for (int reg = 0; reg < 4; ++reg) {
                int m = m0 + wm * 64 + mf * 16 + quad * 4 + reg;
                int bidx = m >> 10;
                int sidx = m & 1023;
                int bh = bidx * HH + hh;
                union { _Float16 h; unsigned short u; } cr, ci;
                cr.h = (_Float16)(Sr[mf][ef][reg] + bb.x);
                ci.h = (_Float16)(Si[mf][ef][reg] + bb.y);
                size_t o = isV ? ((size_t)bh * DHD + col) * SS + sidx
                               : ((size_t)bh * SS + sidx) * DHD + col;
                outP[0 * PL + o] = cr.u;
                outP[1 * PL + o] = ci.u;
            }
        }
    }
}

// ---------------------------------------------------------------------------
// Kernel 2: fp16 MFMA flash attention, S^T formulation.
// Round-5 restructure: 2 barriers/tile + latency hiding.
//   * K double-buffered (prefetch t+1 issued at top of iter t by waves 0-1),
//     V single-buffered (issued same-tile by waves 2-3). Both drain at the
//     post-exp barrier, ~500+ cy after issue (hidden under scores+exp).
//   * native v_exp_f32 via __builtin_amdgcn_exp2f (round-4's exp2f was the
//     precise OCML path — that was the VALU regression).
//   * no setprio (lockstep barrier structure: documented null-to-negative).
// ---------------------------------------------------------------------------
#define AWID 72
__global__ __launch_bounds__(256, 2)
void attn_kernel(const unsigned short* __restrict__ QG, const unsigned short* __restrict__ KG,
                 const unsigned short* __restrict__ VG,
                 unsigned short* __restrict__ ObR, unsigned short* __restrict__ ObI) {
    __shared__ __align__(16) unsigned short Ks[2][2][64 * 64]; // [buf][r,i][k][d] swizzled
    __shared__ __align__(16) unsigned short Vt[2][64 * 64];    // [r,i][d][k] swizzled
    __shared__ __align__(16) unsigned short Ps[2][64 * AWID];  // [r,i][q][k]
    __shared__ float lbuf[2][2][64];                           // [plane][k-half][q]

    const int n   = blockIdx.x;
    const int bh  = (n & 7) * 4 + (n >> 7);       // XCD-local bh group
    const int q0  = ((n >> 3) & 15) * 64;
    const int b   = bh >> 3;
    const int h   = bh & 7;

    const int tid  = threadIdx.x;
    const int w    = tid >> 6;
    const int lane = tid & 63;
    const int quad = lane >> 4;
    const int l15  = lane & 15;
    const int sw   = w & 1;        // q-half (both phases)
    const int tw   = w >> 1;       // k-half (scores) / d-half (PV)

    // ---- DMA staging setup: waves 0,1 own K planes; waves 2,3 own V planes ----
    const int srow = lane >> 3;    // 0..7 (row within 8-row DMA group)
    const int sg   = lane & 7;     // dest granule; source granule = sg^srow
    const bool isK = (w < 2);
    const unsigned short* bpK = nullptr;
    const unsigned short* bpV = nullptr;
    unsigned short* ldV = nullptr;
    if (isK) {
        bpK = KG + (size_t)w * PL + (size_t)bh * SS * DHD + srow * DHD + ((sg ^ srow) << 3);
    } else {
        bpV = VG + (size_t)(w - 2) * PL + (size_t)bh * DHD * SS + srow * SS + ((sg ^ srow) << 3);
        ldV = &Vt[w - 2][0];
    }

#define GLD(SRC, DST) __builtin_amdgcn_global_load_lds( \
        (const __attribute__((address_space(1))) void*)(SRC), \
        (__attribute__((address_space(3))) void*)(DST), 16, 0, 0)

    // ---- prologue: stage K(0) into buf0 ----
    if (isK) {
        unsigned short* ld = &Ks[0][w][0];
        #pragma unroll
        for (int j = 0; j < 8; ++j) GLD(bpK + j * 8 * DHD, ld + j * 512);
    }

    // Q in B-layout registers: lane = q col, quad*8+j = d within 32-window
    half8 qfr[2][2], qfi[2][2], qfmi[2][2];       // [qt][kc]
    #pragma unroll
    for (int qt = 0; qt < 2; ++qt)
        #pragma unroll
        for (int kc = 0; kc < 2; ++kc) {
            size_t qa = ((size_t)bh * SS + q0 + sw * 32 + qt * 16 + l15) * DHD + kc * 32 + quad * 8;
            qfr[qt][kc]  = *(const half8*)(QG + qa);
            qfi[qt][kc]  = *(const half8*)(QG + PL + qa);
            qfmi[qt][kc] = negh(qfi[qt][kc]);
        }

    f32x4 acc[2][2][4];            // [qt][dt][PrVr,PrVi,PiVr,PiVi]
    #pragma unroll
    for (int qt = 0; qt < 2; ++qt)
        #pragma unroll
        for (int dt = 0; dt < 2; ++dt)
            #pragma unroll
            for (int p = 0; p < 4; ++p) acc[qt][dt][p] = (f32x4)0.f;
    float lacc[2][2] = {{0.f, 0.f}, {0.f, 0.f}};  // [qt][plane]

    constexpr float EC = 0.18033688011112042f;    // log2(e)/8

    __syncthreads();               // K(0) staged (drains prologue vmcnt)

    // double-buffer pointer sets (swapped per iteration; register moves only)
    const unsigned short* Kr_c = &Ks[0][0][0];
    const unsigned short* Ki_c = &Ks[0][1][0];
    const unsigned short* Kr_n = &Ks[1][0][0];
    const unsigned short* Ki_n = &Ks[1][1][0];
    unsigned short* kst_nxt = isK ? &Ks[1][w][0] : nullptr;
    unsigned short* kst_alt = isK ? &Ks[0][w][0] : nullptr;

    for (int t = 0; t < 16; ++t) {
        // ---- issue prefetch: K(t+1) -> next buf (waves 0,1); V(t) (waves 2,3)
        if (isK) {
            if (t < 15) {
                const unsigned short* g = bpK + (size_t)(t + 1) * 64 * DHD;
                #pragma unroll
                for (int j = 0; j < 8; ++j) GLD(g + j * 8 * DHD, kst_nxt + j * 512);
            }
        } else {
            const unsigned short* g = bpV + (size_t)t * 64;
            #pragma unroll
            for (int j = 0; j < 8; ++j) GLD(g + j * 8 * SS, ldV + j * 512);
        }

        // ---- scores: S^T[k32][q32] from current K buffer ----
        f32x4 Sr[2][2], Si[2][2];   // [kt2][qt]
        #pragma unroll
        for (int a = 0; a < 2; ++a)
            #pragma unroll
            for (int c = 0; c < 2; ++c) { Sr[a][c] = (f32x4)0.f; Si[a][c] = (f32x4)0.f; }
        #pragma unroll
        for (int kc = 0; kc < 2; ++kc) {
            const int dl = kc * 32 + quad * 8;
            #pragma unroll
            for (int kt2 = 0; kt2 < 2; ++kt2) {
                const int krow = tw * 32 + kt2 * 16 + l15;
                half8 akr = ldh64(Kr_c, krow, dl);
                half8 aki = ldh64(Ki_c, krow, dl);
                #pragma unroll
                for (int qt = 0; qt < 2; ++qt) {
                    MFMA16(Sr[kt2][qt], akr, qfr[qt][kc]);    // K_r . Q_r
                    MFMA16(Sr[kt2][qt], aki, qfmi[qt][kc]);   // -K_i . Q_i
                    MFMA16(Si[kt2][qt], aki, qfr[qt][kc]);    // K_i . Q_r
                    MFMA16(Si[kt2][qt], akr, qfi[qt][kc]);    // K_r . Q_i
                }
            }
        }

        // ---- exp -> P (packed b64, q-major), l partial per lane ----
        #pragma unroll
        for (int kt2 = 0; kt2 < 2; ++kt2)
            #pragma unroll
            for (int qt = 0; qt < 2; ++qt) {
                float er0 = ex2(Sr[kt2][qt][0] * EC), er1 = ex2(Sr[kt2][qt][1] * EC);
                float er2 = ex2(Sr[kt2][qt][2] * EC), er3 = ex2(Sr[kt2][qt][3] * EC);
                float ei0 = ex2(Si[kt2][qt][0] * EC), ei1 = ex2(Si[kt2][qt][1] * EC);
                float ei2 = ex2(Si[kt2][qt][2] * EC), ei3 = ex2(Si[kt2][qt][3] * EC);
                lacc[qt][0] += (er0 + er1) + (er2 + er3);
                lacc[qt][1] += (ei0 + ei1) + (ei2 + ei3);
                const int qrow = sw * 32 + qt * 16 + l15;
                const int kcol = tw * 32 + kt2 * 16 + quad * 4;
                uint2 pr, pi;
                pr.x = cvtpk(er0, er1); pr.y = cvtpk(er2, er3);
                pi.x = cvtpk(ei0, ei1); pi.y = cvtpk(ei2, ei3);
                *(uint2*)&Ps[0][qrow * AWID + kcol] = pr;
                *(uint2*)&Ps[1][qrow * AWID + kcol] = pi;
            }
        __syncthreads();   // SYNC1: Ps ready; drains K(t+1) and V(t) DMAs

        // ---- PV: out tile q32 (sw) x d32 (tw), k64 accumulation ----
        #pragma unroll
        for (int kc = 0; kc < 2; ++kc) {
            half8 ap[2][2];   // [qt][plane]
            #pragma unroll
            for (int qt = 0; qt < 2; ++qt) {
                const int qrow = sw * 32 + qt * 16 + l15;
                ap[qt][0] = *(const half8*)&Ps[0][qrow * AWID + kc * 32 + quad * 8];
                ap[qt][1] = *(const half8*)&Ps[1][qrow * AWID + kc * 32 + quad * 8];
            }
            #pragma unroll
            for (int dt = 0; dt < 2; ++dt) {
                const int drow = tw * 32 + dt * 16 + l15;
                half8 bvr = ldh64(Vt[0], drow, kc * 32 + quad * 8);
                half8 bvi = ldh64(Vt[1], drow, kc * 32 + quad * 8);
                #pragma unroll
                for (int qt = 0; qt < 2; ++qt) {
                    MFMA16(acc[qt][dt][0], ap[qt][0], bvr);
                    MFMA16(acc[qt][dt][1], ap[qt][0], bvi);
                    MFMA16(acc[qt][dt][2], ap[qt][1], bvr);
                    MFMA16(acc[qt][dt][3], ap[qt][1], bvi);
                }
            }
        }
        __syncthreads();   // SYNC2: everyone done with Vt, Ps, and old K buf

        // swap K buffers (register moves)
        const unsigned short* tr;
        tr = Kr_c; Kr_c = Kr_n; Kr_n = tr;
        tr = Ki_c; Ki_c = Ki_n; Ki_n = tr;
        unsigned short* ts = kst_nxt; kst_nxt = kst_alt; kst_alt = ts;
    }
#undef GLD

    // ---- combine l: quad-reduce (lane's k-subset -> full k-half), store ----
    #pragma unroll
    for (int qt = 0; qt < 2; ++qt)
        #pragma unroll
        for (int p = 0; p < 2; ++p) {
            float v = lacc[qt][p];
            v += __shfl_xor(v, 16);
            v += __shfl_xor(v, 32);
            if (lane < 16) lbuf[p][tw][sw * 32 + qt * 16 + lane] = v;
        }
    __syncthreads();

    // ---- epilogue: normalize, combine complex, store fp16 planes ----
    #pragma unroll
    for (int qt = 0; qt < 2; ++qt)
        #pragma unroll
        for (int reg = 0; reg < 4; ++reg) {
            const int qloc = sw * 32 + qt * 16 + quad * 4 + reg;
            const float ir = 1.f / (lbuf[0][0][qloc] + lbuf[0][1][qloc]);
            const float ii = 1.f / (lbuf[1][0][qloc] + lbuf[1][1][qloc]);
            #pragma unroll
            for (int dt = 0; dt < 2; ++dt) {
                const int d = tw * 32 + dt * 16 + l15;
                union { _Float16 h; unsigned short u; } cr, ci;
                cr.h = (_Float16)(acc[qt][dt][0][reg] * ir - acc[qt][dt][3][reg] * ii);
                ci.h = (_Float16)(acc[qt][dt][1][reg] * ir + acc[qt][dt][2][reg] * ii);
                size_t o = ((size_t)b * SS + q0 + qloc) * DD + h * DHD + d;
                ObR[o] = cr.u;
                ObI[o] = ci.u;
            }
        }
}

// ---------------------------------------------------------------------------
// Kernel 3: residual + dual LayerNorm over D (biased var, eps inside sqrt)
// ---------------------------------------------------------------------------
__global__ __launch_bounds__(256)
void ln_kernel(const unsigned short* __restrict__ OrP, const unsigned short* __restrict__ OiP,
               const float2* __restrict__ Qin,
               const float* __restrict__ gr, const float* __restrict__ br,
               const float* __restrict__ gi, const float* __restrict__ bi,
               float2* __restrict__ out) {
    const int row = blockIdx.x;           // b*S + s
    const int tid = threadIdx.x;
    const size_t base = (size_t)row * DD;
    const int e0 = 2 * tid, e1 = 2 * tid + 1;

    union { unsigned int u; _Float16 h[2]; } tr, ti;
    tr.u = *(const unsigned int*)(OrP + base + e0);
    ti.u = *(const unsigned int*)(OiP + base + e0);
    float2 r0 = Qin[base + e0];
    float2 r1 = Qin[base + e1];
    float xr0 = (float)tr.h[0] + r0.x;
    float xr1 = (float)tr.h[1] + r1.x;
    float xi0 = (float)ti.h[0] + r0.y;
    float xi1 = (float)ti.h[1] + r1.y;

    float sr = xr0 + xr1;
    float si = xi0 + xi1;
    float qr = xr0 * xr0 + xr1 * xr1;
    float qi = xi0 * xi0 + xi1 * xi1;
    #pragma unroll
    for (int off = 32; off > 0; off >>= 1) {
        sr += __shfl_down(sr, off);
        si += __shfl_down(si, off);
        qr += __shfl_down(qr, off);
        qi += __shfl_down(qi, off);
    }
    __shared__ float red[4][4];
    __shared__ float stat[4];
    int lane = tid & 63, wid = tid >> 6;
    if (lane == 0) { red[wid][0] = sr; red[wid][1] = si; red[wid][2] = qr; red[wid][3] = qi; }
    __syncthreads();
    if (tid == 0) {
        sr = red[0][0] + red[1][0] + red[2][0] + red[3][0];
        si = red[0][1] + red[1][1] + red[2][1] + red[3][1];
        qr = red[0][2] + red[1][2] + red[2][2] + red[3][2];
        qi = red[0][3] + red[1][3] + red[2][3] + red[3][3];
        float mur = sr * (1.f / DD), mui = si * (1.f / DD);
        float vr = qr * (1.f / DD) - mur * mur;
        float vi = qi * (1.f / DD) - mui * mui;
        stat[0] = mur; stat[1] = mui;
        stat[2] = rsqrtf(vr + LN_EPS); stat[3] = rsqrtf(vi + LN_EPS);
    }
    __syncthreads();
    float mur = stat[0], mui = stat[1], rsr = stat[2], rsi = stat[3];
    out[base + e0] = make_float2((xr0 - mur) * rsr * gr[e0] + br[e0],
                                 (xi0 - mui) * rsi * gi[e0] + bi[e0]);
    out[base + e1] = make_float2((xr1 - mur) * rsr * gr[e1] + br[e1],
                                 (xi1 - mui) * rsi * gi[e1] + bi[e1]);
}

// ---------------------------------------------------------------------------
extern "C" void kernel_launch(void* const* d_in, const int* in_sizes, int n_in,
                              void* d_out, int out_size, void* d_ws, size_t ws_size,
                              hipStream_t stream) {
    const float2* q  = (const float2*)d_in[0];
    const float2* k  = (const float2*)d_in[1];
    const float2* v  = (const float2*)d_in[2];
    const float2* Wq = (const float2*)d_in[3];
    const float2* bq = (const float2*)d_in[4];
    const float2* Wk = (const float2*)d_in[5];
    const float2* bk = (const float2*)d_in[6];
    const float2* Wv = (const float2*)d_in[7];
    const float2* bv = (const float2*)d_in[8];
    const float*  gr = (const float*)d_in[9];
    const float*  br = (const float*)d_in[10];
    const float*  gi = (const float*)d_in[11];
    const float*  bi = (const float*)d_in[12];

    // workspace (fp16 elements): X planes, W planes, Q/K/V planes, Ob planes
    unsigned short* XP  = (unsigned short*)d_ws;           // 3*2*PL (blocked)
    unsigned short* WP  = XP + (size_t)6 * PL;             // 3*2*WPL (blocked)
    unsigned short* QG  = WP + (size_t)6 * WPL;            // 2*PL  [BH][S][64]
    unsigned short* KG  = QG + (size_t)2 * PL;             // 2*PL  [BH][S][64]
    unsigned short* VG  = KG + (size_t)2 * PL;             // 2*PL  [BH][64][S] (transposed)
    unsigned short* ObR = VG + (size_t)2 * PL;             // PL
    unsigned short* ObI = ObR + (size_t)PL;                // PL

    cvt_kernel<<<dim3(4096, 3), 256, 0, stream>>>(q, k, v, XP, PL);
    cvt_kernel<<<dim3(512, 3), 256, 0, stream>>>(Wq, Wk, Wv, WP, WPL);
    proj_kernel<<<dim3(32, 4, 3), 256, 0, stream>>>(XP, WP, bq, bk, bv, QG, KG, VG);
    attn_kernel<<<dim3(512), 256, 0, stream>>>(QG, KG, VG, ObR, ObI);
    ln_kernel<<<dim3(BB * SS), 256, 0, stream>>>(ObR, ObI, q, gr, br, gi, bi, (float2*)d_out);
}